// Round 4
// baseline (213.831 us; speedup 1.0000x reference)
//
#include <hip/hip_runtime.h>
#include <math.h>

typedef float f4 __attribute__((ext_vector_type(4)));

namespace {
constexpr int NZ = 48, NY = 256, NX = 512;
constexpr int SY = NX;           // y stride (elements)
constexpr int SZ = NX * NY;      // z stride (elements)
constexpr int NTOT = NZ * NY * NX;
constexpr int ZCHUNK = 8;        // planes per block; 6 chunks x 128 y-pairs = 768 blocks
constexpr float INV_DX = 1.0f / 100000.0f;
constexpr float INV_DY = 1.0f / 100000.0f;
constexpr float INV_DZ = 1.0f / 500.0f;
}

__device__ __forceinline__ f4 sp(float s) { return (f4){s, s, s, s}; }

__device__ __forceinline__ f4 ldv(const float* __restrict__ f, int e) {
    return *reinterpret_cast<const f4*>(f + e);
}

__device__ __forceinline__ void stv_nt(float* __restrict__ f, int e, f4 val) {
    __builtin_nontemporal_store(val, reinterpret_cast<f4*>(f + e));
}

// ---- x-axis: per-element window [L | C | R], thread covers i = x0..x0+3 ----
__device__ __forceinline__ void grad2x(f4 L, f4 C, f4 R, int x0, float inv_h,
                                       f4& g, f4& gg) {
    const float h1 = inv_h, h2 = 0.5f * inv_h;
    float win[12] = {L[0], L[1], L[2], L[3], C[0], C[1], C[2], C[3],
                     R[0], R[1], R[2], R[3]};
#pragma unroll
    for (int j = 0; j < 4; ++j) {
        g[j]  = (win[5 + j] - win[3 + j]) * h2;
        gg[j] = ((win[6 + j] - win[4 + j]) * h2 - (win[4 + j] - win[2 + j]) * h2) * h2;
    }
    if (x0 == 0) {                       // i==0 and i==1 edge formulas
        g[0]  = (C[1] - C[0]) * h1;
        gg[0] = ((C[2] - C[0]) * h2 - g[0]) * h1;
        gg[1] = ((C[3] - C[1]) * h2 - (C[1] - C[0]) * h1) * h2;
    } else if (x0 == NX - 4) {           // i==n-2 and i==n-1
        gg[2] = ((C[3] - C[2]) * h1 - (C[2] - C[0]) * h2) * h2;
        g[3]  = (C[3] - C[2]) * h1;
        gg[3] = (g[3] - (C[3] - C[1]) * h2) * h1;
    }
}

__device__ __forceinline__ f4 grad1x(f4 L, f4 C, f4 R, int x0, float inv_h) {
    const float h1 = inv_h, h2 = 0.5f * inv_h;
    f4 g;
    g[0] = (C[1] - L[3]) * h2;
    g[1] = (C[2] - C[0]) * h2;
    g[2] = (C[3] - C[1]) * h2;
    g[3] = (R[0] - C[2]) * h2;
    if (x0 == 0)            g[0] = (C[1] - C[0]) * h1;
    else if (x0 == NX - 4)  g[3] = (C[3] - C[2]) * h1;
    return g;
}

// ---- y/z axes: whole-vector stencil, index i uniform across the f4 ----
__device__ __forceinline__ void grad2v(f4 m2, f4 m1, f4 c, f4 p1, f4 p2,
                                       int i, int n, float inv_h, f4& g, f4& gg) {
    const float h1 = inv_h, h2 = 0.5f * inv_h;
    if (i >= 2 && i <= n - 3) {
        g  = (p1 - m1) * sp(h2);
        gg = ((p2 - c) * sp(h2) - (c - m2) * sp(h2)) * sp(h2);
    } else if (i == 0) {
        g  = (p1 - c) * sp(h1);
        gg = ((p2 - c) * sp(h2) - g) * sp(h1);
    } else if (i == 1) {
        g  = (p1 - m1) * sp(h2);
        gg = ((p2 - c) * sp(h2) - (c - m1) * sp(h1)) * sp(h2);
    } else if (i == n - 2) {
        g  = (p1 - m1) * sp(h2);
        gg = ((p1 - c) * sp(h1) - (c - m2) * sp(h2)) * sp(h2);
    } else { // i == n-1
        g  = (c - m1) * sp(h1);
        gg = (g - (c - m2) * sp(h2)) * sp(h1);
    }
}

__device__ __forceinline__ f4 grad1v(f4 m1, f4 c, f4 p1, int i, int n, float inv_h) {
    if (i == 0)     return (p1 - c) * sp(inv_h);
    if (i == n - 1) return (c - m1) * sp(inv_h);
    return (p1 - m1) * sp(0.5f * inv_h);
}

struct Offs {
    int xm, xp;
    int m1y, m2y, p1y, p2y;
    int x0, y;
};

// grad2 field: x/y halos from cache, z from register window w0..w4 (= z-2..z+2)
__device__ __forceinline__ void axes_grad2(const float* __restrict__ f, int e,
                                           const Offs& o, f4 w0, f4 w1, f4 w2,
                                           f4 w3, f4 w4, int z,
                                           f4& gx, f4& gy, f4& gz, f4& lap) {
    f4 L = ldv(f, e + o.xm);
    f4 R = ldv(f, e + o.xp);
    f4 ggx, ggy, ggz;
    grad2x(L, w2, R, o.x0, INV_DX, gx, ggx);
    grad2v(ldv(f, e + o.m2y), ldv(f, e + o.m1y), w2, ldv(f, e + o.p1y),
           ldv(f, e + o.p2y), o.y, NY, INV_DY, gy, ggy);
    grad2v(w0, w1, w2, w3, w4, z, NZ, INV_DZ, gz, ggz);
    lap = ggx + ggy + ggz;
}

// grad1 field: x/y halos from cache, z from register window m1,c,p1 (= z-1..z+1)
__device__ __forceinline__ void axes_grad1(const float* __restrict__ f, int e,
                                           const Offs& o, f4 m1, f4 c, f4 p1,
                                           int z, f4& gx, f4& gy, f4& gz) {
    f4 L = ldv(f, e + o.xm);
    f4 R = ldv(f, e + o.xp);
    gx = grad1x(L, c, R, o.x0, INV_DX);
    gy = grad1v(ldv(f, e + o.m1y), c, ldv(f, e + o.p1y), o.y, NY, INV_DY);
    gz = grad1v(m1, c, p1, z, NZ, INV_DZ);
}

__global__ __launch_bounds__(256)
void pe_zmarch(const float* __restrict__ u, const float* __restrict__ v,
               const float* __restrict__ w, const float* __restrict__ T,
               const float* __restrict__ q, const float* __restrict__ p,
               const float* __restrict__ rho,
               const float* __restrict__ F_u, const float* __restrict__ F_v,
               const float* __restrict__ F_w, const float* __restrict__ Q,
               const float* __restrict__ S,
               const float* __restrict__ nu_p, const float* __restrict__ kappa_p,
               float* __restrict__ out) {
    // 768 blocks. XCD-aware: bid&7 = XCD; each XCD owns a 32-row y-band,
    // sweeping its 6 z-chunks; the 16 y-pair blocks of one chunk run together
    // so y-halos and the marching plane window stay in the XCD's 4MB L2.
    const int bid = blockIdx.x;
    const int xcd = bid & 7;
    const int j = bid >> 3;                        // 0..95
    const int zc = j >> 4;                         // 0..5
    const int yp = (xcd << 4) | (j & 15);          // y-pair 0..127
    const int y = (yp << 1) | (threadIdx.x >> 7);  // row 0..255
    const int x0 = (threadIdx.x & 127) << 2;
    const int z0 = zc * ZCHUNK;
    const int ebase = y * SY + x0;

    Offs o;
    o.x0 = x0; o.y = y;
    o.xm = (x0 > 0) ? -4 : 0;
    o.xp = (x0 < NX - 4) ? 4 : 0;
    o.m1y = (y > 0) ? -SY : 0;
    o.m2y = (y > 1) ? -2 * SY : o.m1y;
    o.p1y = (y < NY - 1) ? SY : 0;
    o.p2y = (y < NY - 2) ? 2 * SY : o.p1y;

    const float snu = nu_p[0];
    const float skap = kappa_p[0];
    const float lat = -1.57079632679f + (3.14159265359f / 255.0f) * (float)y;
    const float fc = 2.0f * 7.2921e-5f * __sinf(lat);

    // ---- prologue: fill register plane-windows (clamped low) ----
    f4 Wu[5], Wv[5], Ww[5], WT[5];
    f4 Wp[3], Wr[3], Wq[3];
#pragma unroll
    for (int k = 0; k < 5; ++k) {
        int zp = z0 - 2 + k; zp = zp < 0 ? 0 : zp;
        const int e = zp * SZ + ebase;
        Wu[k] = ldv(u, e); Wv[k] = ldv(v, e);
        Ww[k] = ldv(w, e); WT[k] = ldv(T, e);
    }
#pragma unroll
    for (int k = 0; k < 3; ++k) {
        int zp = z0 - 1 + k; zp = zp < 0 ? 0 : zp;
        const int e = zp * SZ + ebase;
        Wp[k] = ldv(p, e); Wr[k] = ldv(rho, e); Wq[k] = ldv(q, e);
    }

    for (int z = z0; z < z0 + ZCHUNK; ++z) {
        const int e = z * SZ + ebase;

        // ---- prefetch next window planes (used only after the shift) ----
        int zp2 = z + 3; zp2 = zp2 > NZ - 1 ? NZ - 1 : zp2;
        int zp1 = z + 2; zp1 = zp1 > NZ - 1 ? NZ - 1 : zp1;
        const int e2 = zp2 * SZ + ebase;
        const int e1 = zp1 * SZ + ebase;
        const f4 pu = ldv(u, e2), pv = ldv(v, e2), pw = ldv(w, e2), pT = ldv(T, e2);
        const f4 pp = ldv(p, e1), pr = ldv(rho, e1), pq = ldv(q, e1);

        // ---- compute plane z ----
        const f4 uc = Wu[2], vc = Wv[2], wc = Ww[2];
        f4 gx, gy, gz, lap;

        axes_grad2(u, e, o, Wu[0], Wu[1], Wu[2], Wu[3], Wu[4], z, gx, gy, gz, lap);
        f4 du_dx = gx;
        f4 acc_u = sp(snu) * lap - (uc * gx + vc * gy + wc * gz);

        axes_grad2(v, e, o, Wv[0], Wv[1], Wv[2], Wv[3], Wv[4], z, gx, gy, gz, lap);
        f4 dv_dy = gy;
        f4 acc_v = sp(snu) * lap - (uc * gx + vc * gy + wc * gz);

        axes_grad2(w, e, o, Ww[0], Ww[1], Ww[2], Ww[3], Ww[4], z, gx, gy, gz, lap);
        f4 dw_dz = gz;
        f4 acc_w = sp(snu) * lap - (uc * gx + vc * gy + wc * gz);

        const f4 div = du_dx + dv_dy + dw_dz;

        const f4 Tc = WT[2];
        axes_grad2(T, e, o, WT[0], WT[1], WT[2], WT[3], WT[4], z, gx, gy, gz, lap);
        f4 acc_T = sp(skap) * lap - (uc * gx + vc * gy + wc * gz);

        const f4 rhoc = Wr[1];
        axes_grad1(rho, e, o, Wr[0], Wr[1], Wr[2], z, gx, gy, gz);
        f4 acc_rho = -rhoc * div - uc * gx - vc * gy - wc * gz;

        const f4 pc = Wp[1];
        axes_grad1(p, e, o, Wp[0], Wp[1], Wp[2], z, gx, gy, gz);
        const f4 inv_rs = sp(1.0f) / (rhoc + sp(1e-10f));
        acc_u -= gx * inv_rs;
        acc_v -= gy * inv_rs;
        acc_w -= gz * inv_rs;
        acc_T += sp(287.0f / 1004.0f) * Tc * wc * gz / (pc + sp(1e-10f));

        const f4 qc = Wq[1];
        axes_grad1(q, e, o, Wq[0], Wq[1], Wq[2], z, gx, gy, gz);
        f4 acc_q = -(uc * gx + vc * gy + wc * gz);

        acc_u += sp(fc) * vc + ldv(F_u, e);
        acc_v += ldv(F_v, e) - sp(fc) * uc;
        acc_w += ldv(F_w, e) - sp(9.80665f);
        acc_T += ldv(Q, e) * sp(1.0f / 1004.0f);
        acc_q += ldv(S, e);

        const f4 acc_p = sp(287.0f) * (rhoc * acc_T + Tc * acc_rho);

        stv_nt(out, 0 * NTOT + e, acc_u);
        stv_nt(out, 1 * NTOT + e, acc_v);
        stv_nt(out, 2 * NTOT + e, acc_w);
        stv_nt(out, 3 * NTOT + e, acc_T);
        stv_nt(out, 4 * NTOT + e, acc_q);
        stv_nt(out, 5 * NTOT + e, acc_p);
        stv_nt(out, 6 * NTOT + e, acc_rho);

        // ---- shift windows, append prefetched planes (static indices) ----
        Wu[0] = Wu[1]; Wu[1] = Wu[2]; Wu[2] = Wu[3]; Wu[3] = Wu[4]; Wu[4] = pu;
        Wv[0] = Wv[1]; Wv[1] = Wv[2]; Wv[2] = Wv[3]; Wv[3] = Wv[4]; Wv[4] = pv;
        Ww[0] = Ww[1]; Ww[1] = Ww[2]; Ww[2] = Ww[3]; Ww[3] = Ww[4]; Ww[4] = pw;
        WT[0] = WT[1]; WT[1] = WT[2]; WT[2] = WT[3]; WT[3] = WT[4]; WT[4] = pT;
        Wp[0] = Wp[1]; Wp[1] = Wp[2]; Wp[2] = pp;
        Wr[0] = Wr[1]; Wr[1] = Wr[2]; Wr[2] = pr;
        Wq[0] = Wq[1]; Wq[1] = Wq[2]; Wq[2] = pq;
    }
}

extern "C" void kernel_launch(void* const* d_in, const int* in_sizes, int n_in,
                              void* d_out, int out_size, void* d_ws, size_t ws_size,
                              hipStream_t stream) {
    const float* u     = (const float*)d_in[0];
    const float* v     = (const float*)d_in[1];
    const float* w     = (const float*)d_in[2];
    const float* T     = (const float*)d_in[3];
    const float* q     = (const float*)d_in[4];
    const float* p     = (const float*)d_in[5];
    const float* rho   = (const float*)d_in[6];
    const float* F_u   = (const float*)d_in[7];
    const float* F_v   = (const float*)d_in[8];
    const float* F_w   = (const float*)d_in[9];
    const float* Q     = (const float*)d_in[10];
    const float* S     = (const float*)d_in[11];
    const float* nu    = (const float*)d_in[12];
    const float* kappa = (const float*)d_in[13];
    float* out = (float*)d_out;

    const int grid = (NZ / ZCHUNK) * (NY / 2);   // 6 * 128 = 768 blocks
    pe_zmarch<<<grid, 256, 0, stream>>>(u, v, w, T, q, p, rho,
                                        F_u, F_v, F_w, Q, S, nu, kappa, out);
}